// Round 8
// baseline (506.547 us; speedup 1.0000x reference)
//
#include <hip/hip_runtime.h>
#include <stdint.h>

typedef __bf16 bf16x8 __attribute__((ext_vector_type(8)));
typedef float f32x4 __attribute__((ext_vector_type(4)));
typedef unsigned short ushort8v __attribute__((ext_vector_type(8)));

__device__ __forceinline__ void gload_lds16(const void* g, void* l) {
  __builtin_amdgcn_global_load_lds(
      (const __attribute__((address_space(1))) void*)g,
      (__attribute__((address_space(3))) void*)l, 16, 0, 0);
}

__device__ __forceinline__ unsigned short f2bf(float f) {
  union { float f; unsigned int u; } x; x.f = f;
  unsigned int r = x.u + 0x7FFFu + ((x.u >> 16) & 1u);
  return (unsigned short)(r >> 16);
}

__device__ __forceinline__ float ftanh(float x) {
  float ax = fabsf(x);
  float e = __expf(-2.0f * ax);
  float r = (1.0f - e) / (1.0f + e);
  return copysignf(r, x);
}

// -------- W1 f32 -> bf16, PRE-SWIZZLED 16 KB chunk layout --------
// chunk p (p = ((hh*4+kq)*8+c8)*2+kh) covers a in [hh*512+c8*64, +64),
// k in [kq*256+kh*128, +128). Within a chunk, dest byte d holds source
// k-offset (d&255) ^ ((row&15)<<4), row = d>>8  (inverse of read swizzle).
__global__ __launch_bounds__(256) void w1cvt_kernel(
    const float* __restrict__ W1, unsigned short* __restrict__ w1b) {
  const int g = blockIdx.x * 256 + threadIdx.x; /* 16-B piece id */
  const int p = g >> 10;
  const int q = g & 1023;
  const int row = q >> 4;
  const int off = (q & 15) * 16;
  const int srcoff = off ^ ((row & 15) << 4);
  const int kh = p & 1, c8 = (p >> 1) & 7, kq = (p >> 4) & 3, hh = p >> 6;
  const int a = hh * 512 + c8 * 64 + row;
  const int k = kq * 256 + kh * 128 + (srcoff >> 1);
  const float* src = W1 + (size_t)a * 1024 + k;
  const float4 v0 = *(const float4*)src;
  const float4 v1 = *(const float4*)(src + 4);
  ushort8v o;
  o[0] = f2bf(v0.x); o[1] = f2bf(v0.y); o[2] = f2bf(v0.z); o[3] = f2bf(v0.w);
  o[4] = f2bf(v1.x); o[5] = f2bf(v1.y); o[6] = f2bf(v1.z); o[7] = f2bf(v1.w);
  *((ushort8v*)w1b + g) = o;
}

// ---------------- u[b][a] = sum_d dec[b][d] * W2[a][d] ----------------
__global__ __launch_bounds__(256) void dec_proj_kernel(
    const float* __restrict__ dec, const float* __restrict__ W2,
    float* __restrict__ u) {
  __shared__ __align__(16) float w2s[1024];
  const int a = blockIdx.x;
  const int t = threadIdx.x;
  *(float4*)(w2s + t * 4) = *(const float4*)(W2 + (size_t)a * 1024 + t * 4);
  __syncthreads();
  const int wid = t >> 6, l = t & 63;
  for (int bi = 0; bi < 8; ++bi) {
    const int b = wid * 8 + bi;
    const float* dp = dec + (size_t)b * 1024;
    float acc = 0.f;
#pragma unroll
    for (int i = 0; i < 4; ++i) {
      const int k = i * 256 + l * 4;
      const float4 dv = *(const float4*)(dp + k);
      const float4 wv = *(const float4*)(w2s + k);
      acc = fmaf(dv.x, wv.x, acc); acc = fmaf(dv.y, wv.y, acc);
      acc = fmaf(dv.z, wv.z, acc); acc = fmaf(dv.w, wv.w, acc);
    }
#pragma unroll
    for (int m = 1; m < 64; m <<= 1) acc += __shfl_xor(acc, m, 64);
    if (l == 0) u[(size_t)b * 1024 + a] = acc;
  }
}

// ---------------- fused scores: v . tanh(enc@W1^T + u) ----------------
// grid 1024 (64 rows each), 512 threads (8 waves = 2 wr x 4 wc).
// T3+T4: 3x16KB B-buffers, stages issued 2 phases ahead via global_load_lds
// from pre-swizzled w1b; per phase: s_waitcnt vmcnt(2) -> raw s_barrier ->
// issue stage(p+2) -> MFMA (T5 setprio). __syncthreads only at the 8 enc
// re-stagings. LDS 65.5 KB -> 2 blocks/CU.
__global__ __launch_bounds__(512, 4) void scores_kernel(
    const float* __restrict__ enc, const unsigned short* __restrict__ w1b,
    const float* __restrict__ u, const float* __restrict__ vvec,
    float* __restrict__ out) {
  __shared__ __align__(16) char encL[32768];
  __shared__ __align__(16) char Bl[49152];
  __shared__ __align__(16) float sred[256];

  const int t = threadIdx.x;
  const int bid = blockIdx.x;
  const int m0 = bid * 64;
  const int b = bid >> 5; /* 32 blocks per batch (2048/64 rows) */
  const int l = t & 63, wid = t >> 6;
  const int wr = wid >> 2, wc = wid & 3;
  const int lm = l & 15, lg = l >> 4;

  const int row_a0 = wr * 32 + lm; /* rowfrag1 = +16: same (row&15) bits */
  const int aswz = lm << 4;
  const int abase0 = row_a0 * 512;
  const int bbase = (wc * 16 + lm) * 256; /* B row stride = 256 B */
  const int bswz = lm << 4;
  const char* w1c = (const char*)w1b;
  const float* ub = u + (size_t)b * 1024;

  const int sbase0 = wid * 2048;
  const int sbase1 = wid * 2048 + 1024;
  const int glane = l * 16;

  f32x4 rowp0 = {0.f, 0.f, 0.f, 0.f}, rowp1 = {0.f, 0.f, 0.f, 0.f};

  // prologue: stage chunk 0 -> buf0, chunk 1 -> buf1 (outstanding = 4)
  gload_lds16(w1c + sbase0 + glane, Bl + sbase0);
  gload_lds16(w1c + sbase1 + glane, Bl + sbase1);
  gload_lds16(w1c + 16384 + sbase0 + glane, Bl + 16384 + sbase0);
  gload_lds16(w1c + 16384 + sbase1 + glane, Bl + 16384 + sbase1);

  int p = 0;    /* global phase/chunk = ((hh*4+kq)*8+c8)*2+kh */
  int bsel = 0; /* p % 3 */
  for (int hh = 0; hh < 2; ++hh) {
    f32x4 acc[8][2];
#pragma unroll
    for (int c1 = 0; c1 < 8; ++c1)
#pragma unroll
      for (int c2 = 0; c2 < 2; ++c2) acc[c1][c2] = (f32x4){0.f, 0.f, 0.f, 0.f};

    for (int kq = 0; kq < 4; ++kq) {
#pragma unroll
      for (int c8 = 0; c8 < 8; ++c8) {
#pragma unroll
        for (int kh = 0; kh < 2; ++kh) {
          // ---- phase start: own stage(p) retired, then publish ----
          asm volatile("s_waitcnt vmcnt(2)" ::: "memory");
          __builtin_amdgcn_s_barrier();
          __builtin_amdgcn_sched_barrier(0);
          // ---- issue stage(p+2) -> buf (p+2)%3 (dummy-wrapped at tail) ----
          {
            const int pn = (p + 2) & 127;
            const char* src = w1c + (size_t)pn * 16384;
            int nb = bsel + 2; nb = (nb >= 3) ? nb - 3 : nb;
            const int nbuf = nb * 16384;
            gload_lds16(src + sbase0 + glane, Bl + nbuf + sbase0);
            gload_lds16(src + sbase1 + glane, Bl + nbuf + sbase1);
          }
          if (c8 == 0 && kh == 0) {
            // ---- stage enc quarter: 64 x 256, f32 -> bf16, swizzled ----
#pragma unroll
            for (int it = 0; it < 4; ++it) {
              const int c = it * 512 + t;
              const int row = c >> 5;
              const int k0 = (c & 31) * 8;
              const float* g = enc + (size_t)(m0 + row) * 1024 + kq * 256 + k0;
              const float4 v0 = *(const float4*)g;
              const float4 v1 = *(const float4*)(g + 4);
              ushort8v o;
              o[0] = f2bf(v0.x); o[1] = f2bf(v0.y); o[2] = f2bf(v0.z); o[3] = f2bf(v0.w);
              o[4] = f2bf(v1.x); o[5] = f2bf(v1.y); o[6] = f2bf(v1.z); o[7] = f2bf(v1.w);
              const int dest = row * 512 + ((k0 * 2) ^ ((row & 15) << 4));
              *(ushort8v*)(encL + dest) = o;
            }
            __syncthreads(); /* full drain: encL + already-landed stages */
          }
          // ---- compute phase p from buf bsel ----
          const int cbuf = bsel * 16384;
          __builtin_amdgcn_s_setprio(1);
#pragma unroll
          for (int kk = 0; kk < 4; ++kk) {
            const int koff = (((kh * 4 + kk) * 64) + lg * 16) ^ aswz;
            const bf16x8 a0 = *(const bf16x8*)(encL + abase0 + koff);
            const bf16x8 a1 = *(const bf16x8*)(encL + abase0 + 8192 + koff);
            const bf16x8 b0 = *(const bf16x8*)(Bl + cbuf + bbase +
                                               ((kk * 64 + lg * 16) ^ bswz));
            acc[c8][0] = __builtin_amdgcn_mfma_f32_16x16x32_bf16(a0, b0, acc[c8][0], 0, 0, 0);
            acc[c8][1] = __builtin_amdgcn_mfma_f32_16x16x32_bf16(a1, b0, acc[c8][1], 0, 0, 0);
          }
          __builtin_amdgcn_s_setprio(0);
          __builtin_amdgcn_sched_barrier(0);
          ++p;
          bsel = (bsel + 1 == 3) ? 0 : bsel + 1;
        }
      }
    }

    // half-epilogue: tanh + v-weighted column reduction (registers only)
#pragma unroll
    for (int c8 = 0; c8 < 8; ++c8) {
      const int colA = hh * 512 + c8 * 64 + wc * 16 + lm;
      const float uu = ub[colA], vv = vvec[colA];
#pragma unroll
      for (int j = 0; j < 4; ++j) {
        rowp0[j] += ftanh(acc[c8][0][j] + uu) * vv;
        rowp1[j] += ftanh(acc[c8][1][j] + uu) * vv;
      }
    }
  }

  // reduce over the 16 col-lanes (lm) of each fragment group
#pragma unroll
  for (int m = 1; m < 16; m <<= 1) {
#pragma unroll
    for (int j = 0; j < 4; ++j) {
      rowp0[j] += __shfl_xor(rowp0[j], m, 64);
      rowp1[j] += __shfl_xor(rowp1[j], m, 64);
    }
  }
  if (lm == 0) {
#pragma unroll
    for (int j = 0; j < 4; ++j) {
      sred[wc * 64 + wr * 32 + lg * 4 + j] = rowp0[j];
      sred[wc * 64 + wr * 32 + 16 + lg * 4 + j] = rowp1[j];
    }
  }
  __syncthreads();
  if (t < 64) {
    out[32768 + m0 + t] =
        sred[t] + sred[64 + t] + sred[128 + t] + sred[192 + t];
  }
}

// ---------------- masked softmax over L, in place on out[32768..] --------
__global__ __launch_bounds__(256) void softmax_kernel(
    float* __restrict__ out, const int* __restrict__ mask) {
  __shared__ float wred[4];
  const int bidx = blockIdx.x;
  const int t = threadIdx.x;
  float* sc = out + 32768 + (size_t)bidx * 2048;
  const int* mk = mask + (size_t)bidx * 2048;
  const float4 s0 = *(const float4*)(sc + t * 8);
  const float4 s1 = *(const float4*)(sc + t * 8 + 4);
  const int4 q0 = *(const int4*)(mk + t * 8);
  const int4 q1 = *(const int4*)(mk + t * 8 + 4);
  float v[8] = {s0.x, s0.y, s0.z, s0.w, s1.x, s1.y, s1.z, s1.w};
  int q[8] = {q0.x, q0.y, q0.z, q0.w, q1.x, q1.y, q1.z, q1.w};
  float mx = -3.0e38f;
#pragma unroll
  for (int j = 0; j < 8; ++j) if (q[j] != 0) mx = fmaxf(mx, v[j]);
#pragma unroll
  for (int m = 1; m < 64; m <<= 1) mx = fmaxf(mx, __shfl_xor(mx, m, 64));
  if ((t & 63) == 0) wred[t >> 6] = mx;
  __syncthreads();
  mx = fmaxf(fmaxf(wred[0], wred[1]), fmaxf(wred[2], wred[3]));
  __syncthreads();
  float pp[8]; float sum = 0.f;
#pragma unroll
  for (int j = 0; j < 8; ++j) {
    pp[j] = (q[j] != 0) ? __expf(v[j] - mx) : 0.f;
    sum += pp[j];
  }
#pragma unroll
  for (int m = 1; m < 64; m <<= 1) sum += __shfl_xor(sum, m, 64);
  if ((t & 63) == 0) wred[t >> 6] = sum;
  __syncthreads();
  sum = (wred[0] + wred[1]) + (wred[2] + wred[3]);
  const float inv = 1.0f / sum;
  const float4 o0 = {pp[0] * inv, pp[1] * inv, pp[2] * inv, pp[3] * inv};
  const float4 o1 = {pp[4] * inv, pp[5] * inv, pp[6] * inv, pp[7] * inv};
  *(float4*)(sc + t * 8) = o0;
  *(float4*)(sc + t * 8 + 4) = o1;
}

// ---------------- context[b][e] = sum_l attn[b][l] * enc[b][l][e] --------
__global__ __launch_bounds__(256) void context_kernel(
    const float* __restrict__ enc, float* __restrict__ out) {
  __shared__ __align__(16) float attnS[2048];
  __shared__ __align__(16) float red[8 * 128];
  const int bid = blockIdx.x;
  const int b = bid >> 3, ec = bid & 7;
  const int e0 = ec * 128;
  const int t = threadIdx.x;
  const float* attn = out + 32768 + (size_t)b * 2048;
#pragma unroll
  for (int i = 0; i < 8; ++i) attnS[i * 256 + t] = attn[i * 256 + t];
  __syncthreads();
  const int el = (t & 31) * 4;
  const int ls = t >> 5;
  f32x4 acc = {0.f, 0.f, 0.f, 0.f};
  const float* ebase = enc + (size_t)b * 2048 * 1024 + e0 + el;
  for (int l2 = ls; l2 < 2048; l2 += 8) {
    const float a = attnS[l2];
    const float4 ev = *(const float4*)(ebase + (size_t)l2 * 1024);
    acc[0] = fmaf(a, ev.x, acc[0]);
    acc[1] = fmaf(a, ev.y, acc[1]);
    acc[2] = fmaf(a, ev.z, acc[2]);
    acc[3] = fmaf(a, ev.w, acc[3]);
  }
  *(f32x4*)(red + ls * 128 + el) = acc;
  __syncthreads();
  if (t < 128) {
    float s = 0.f;
#pragma unroll
    for (int i = 0; i < 8; ++i) s += red[i * 128 + t];
    out[(size_t)b * 1024 + e0 + t] = s;
  }
}

extern "C" void kernel_launch(void* const* d_in, const int* in_sizes, int n_in,
                              void* d_out, int out_size, void* d_ws,
                              size_t ws_size, hipStream_t stream) {
  const float* enc = (const float*)d_in[0];
  const float* dec = (const float*)d_in[1];
  const int* mask = (const int*)d_in[2];
  const float* W1 = (const float*)d_in[3];
  const float* W2 = (const float*)d_in[4];
  const float* v = (const float*)d_in[5];
  float* out = (float*)d_out;
  char* ws = (char*)d_ws;
  unsigned short* w1b = (unsigned short*)ws; /* 2 MB pre-swizzled bf16 W1 */
  float* u = (float*)(ws + (2u << 20));      /* 128 KB dec projection */

  w1cvt_kernel<<<512, 256, 0, stream>>>(W1, w1b);
  dec_proj_kernel<<<1024, 256, 0, stream>>>(dec, W2, u);
  scores_kernel<<<1024, 512, 0, stream>>>(enc, w1b, u, v, out);
  softmax_kernel<<<32, 256, 0, stream>>>(out, mask);
  context_kernel<<<256, 256, 0, stream>>>(enc, out);
}

// Round 9
// 343.195 us; speedup vs baseline: 1.4760x; 1.4760x over previous
//
#include <hip/hip_runtime.h>
#include <stdint.h>

typedef __bf16 bf16x8 __attribute__((ext_vector_type(8)));
typedef float f32x4 __attribute__((ext_vector_type(4)));
typedef unsigned short ushort8v __attribute__((ext_vector_type(8)));

__device__ __forceinline__ void gload_lds16(const void* g, void* l) {
  __builtin_amdgcn_global_load_lds(
      (const __attribute__((address_space(1))) void*)g,
      (__attribute__((address_space(3))) void*)l, 16, 0, 0);
}

__device__ __forceinline__ unsigned short f2bf(float f) {
  union { float f; unsigned int u; } x; x.f = f;
  unsigned int r = x.u + 0x7FFFu + ((x.u >> 16) & 1u);
  return (unsigned short)(r >> 16);
}

__device__ __forceinline__ float ftanh(float x) {
  float ax = fabsf(x);
  float e = __expf(-2.0f * ax);
  float r = (1.0f - e) / (1.0f + e);
  return copysignf(r, x);
}

// -------- W1 f32 -> bf16, PRE-SWIZZLED 16 KB chunk layout --------
// chunk p = (hh*8 + k8)*8 + c8 covers a in [hh*512 + c8*64, +64),
// k in [k8*128, +128). Within a chunk (64 rows x 256 B), dest byte d
// holds source k-byte (d&255) ^ ((row&15)<<4), row = d>>8 (inverse of
// the read swizzle), so LINEAR global->LDS copy + swizzled read works.
__global__ __launch_bounds__(256) void w1cvt_kernel(
    const float* __restrict__ W1, unsigned short* __restrict__ w1b) {
  const int g = blockIdx.x * 256 + threadIdx.x; /* 16-B piece id */
  const int p = g >> 10;
  const int q = g & 1023;
  const int row = q >> 4;
  const int off = (q & 15) * 16;
  const int srcoff = off ^ ((row & 15) << 4);
  const int c8 = p & 7, k8 = (p >> 3) & 7, hh = p >> 6;
  const int a = hh * 512 + c8 * 64 + row;
  const int k = k8 * 128 + (srcoff >> 1);
  const float* src = W1 + (size_t)a * 1024 + k;
  const float4 v0 = *(const float4*)src;
  const float4 v1 = *(const float4*)(src + 4);
  ushort8v o;
  o[0] = f2bf(v0.x); o[1] = f2bf(v0.y); o[2] = f2bf(v0.z); o[3] = f2bf(v0.w);
  o[4] = f2bf(v1.x); o[5] = f2bf(v1.y); o[6] = f2bf(v1.z); o[7] = f2bf(v1.w);
  *((ushort8v*)w1b + g) = o;
}

// ---------------- u[b][a] = sum_d dec[b][d] * W2[a][d] ----------------
__global__ __launch_bounds__(256) void dec_proj_kernel(
    const float* __restrict__ dec, const float* __restrict__ W2,
    float* __restrict__ u) {
  __shared__ __align__(16) float w2s[1024];
  const int a = blockIdx.x;
  const int t = threadIdx.x;
  *(float4*)(w2s + t * 4) = *(const float4*)(W2 + (size_t)a * 1024 + t * 4);
  __syncthreads();
  const int wid = t >> 6, l = t & 63;
  for (int bi = 0; bi < 8; ++bi) {
    const int b = wid * 8 + bi;
    const float* dp = dec + (size_t)b * 1024;
    float acc = 0.f;
#pragma unroll
    for (int i = 0; i < 4; ++i) {
      const int k = i * 256 + l * 4;
      const float4 dv = *(const float4*)(dp + k);
      const float4 wv = *(const float4*)(w2s + k);
      acc = fmaf(dv.x, wv.x, acc); acc = fmaf(dv.y, wv.y, acc);
      acc = fmaf(dv.z, wv.z, acc); acc = fmaf(dv.w, wv.w, acc);
    }
#pragma unroll
    for (int m = 1; m < 64; m <<= 1) acc += __shfl_xor(acc, m, 64);
    if (l == 0) u[(size_t)b * 1024 + a] = acc;
  }
}

// ---------------- fused scores: v . tanh(enc@W1^T + u) ----------------
// grid 1024 (64 rows each), 512 threads (8 waves = 2 wr x 4 wc).
// T3+T4 counted-vmcnt: 3x16KB B-buffers, stages issued 2 phases ahead
// (global_load_lds from pre-swizzled w1b). Per phase: s_waitcnt vmcnt(2)
// -> raw s_barrier -> issue stage(p+2) -> 8 MFMA (T5 setprio).
// enc: 64x128 K-eighth (16 KB), re-staged at 16 of 128 phase boundaries
// (those use a full __syncthreads drain).
// LDS 66560 B (= R7's proven footprint) -> 2 blocks/CU.
__global__ __launch_bounds__(512, 4) void scores_kernel(
    const float* __restrict__ enc, const unsigned short* __restrict__ w1b,
    const float* __restrict__ u, const float* __restrict__ vvec,
    float* __restrict__ out) {
  __shared__ __align__(16) char encL[16384];
  __shared__ __align__(16) char Bl[49152];
  __shared__ __align__(16) float sred[256];

  const int t = threadIdx.x;
  const int bid = blockIdx.x;
  const int m0 = bid * 64;
  const int b = bid >> 5; /* 32 blocks per batch (2048/64 rows) */
  const int l = t & 63, wid = t >> 6;
  const int wr = wid >> 2, wc = wid & 3;
  const int lm = l & 15, lg = l >> 4;

  const int row_a0 = wr * 32 + lm; /* rowfrag1 = +16: same (row&15) bits */
  const int aswz = lm << 4;
  const int abase0 = row_a0 * 256;        /* enc row stride 256 B */
  const int bbase = (wc * 16 + lm) * 256; /* B row stride 256 B */
  const int bswz = lm << 4;
  const char* w1c = (const char*)w1b;
  const float* ub = u + (size_t)b * 1024;

  const int sbase0 = wid * 2048;
  const int sbase1 = wid * 2048 + 1024;
  const int glane = l * 16;

  f32x4 rowp0 = {0.f, 0.f, 0.f, 0.f}, rowp1 = {0.f, 0.f, 0.f, 0.f};

  // prologue: stage chunk 0 -> buf0, chunk 1 -> buf1 (outstanding = 4)
  gload_lds16(w1c + sbase0 + glane, Bl + sbase0);
  gload_lds16(w1c + sbase1 + glane, Bl + sbase1);
  gload_lds16(w1c + 16384 + sbase0 + glane, Bl + 16384 + sbase0);
  gload_lds16(w1c + 16384 + sbase1 + glane, Bl + 16384 + sbase1);

  const char* nextsrc = w1c + 2 * 16384; /* chunk p+2 source, wraps */
  int bsel = 0; /* current buf = p%3 */
  int nb = 2;   /* buf for p+2 */

  for (int hh = 0; hh < 2; ++hh) {
    f32x4 acc[8][2];
#pragma unroll
    for (int c1 = 0; c1 < 8; ++c1)
#pragma unroll
      for (int c2 = 0; c2 < 2; ++c2) acc[c1][c2] = (f32x4){0.f, 0.f, 0.f, 0.f};

    for (int k8 = 0; k8 < 8; ++k8) {
#pragma unroll
      for (int c8 = 0; c8 < 8; ++c8) {
        // ---- phase top: own stage(p) retired; all waves aligned ----
        asm volatile("s_waitcnt vmcnt(2)" ::: "memory");
        __builtin_amdgcn_s_barrier();
        // ---- issue stage(p+2) into the third buffer ----
        gload_lds16(nextsrc + sbase0 + glane, Bl + nb * 16384 + sbase0);
        gload_lds16(nextsrc + sbase1 + glane, Bl + nb * 16384 + sbase1);
        nextsrc += 16384;
        if (nextsrc == w1c + 2097152) nextsrc = w1c; /* tail dummies wrap */
        if (c8 == 0) {
          // ---- stage enc eighth: 64 rows x 128 k, f32 -> bf16 ----
#pragma unroll
          for (int it = 0; it < 2; ++it) {
            const int c = it * 512 + t;
            const int row = c >> 4;
            const int k0 = (c & 15) * 8;
            const float* g = enc + (size_t)(m0 + row) * 1024 + k8 * 128 + k0;
            const float4 v0 = *(const float4*)g;
            const float4 v1 = *(const float4*)(g + 4);
            ushort8v o;
            o[0] = f2bf(v0.x); o[1] = f2bf(v0.y); o[2] = f2bf(v0.z); o[3] = f2bf(v0.w);
            o[4] = f2bf(v1.x); o[5] = f2bf(v1.y); o[6] = f2bf(v1.z); o[7] = f2bf(v1.w);
            const int dest = row * 256 + ((k0 * 2) ^ ((row & 15) << 4));
            *(ushort8v*)(encL + dest) = o;
          }
          __syncthreads(); /* full drain: encL visible (stages land too) */
        }
        // ---- compute phase p from buf bsel ----
        const int cbuf = bsel * 16384;
        __builtin_amdgcn_s_setprio(1);
#pragma unroll
        for (int kk = 0; kk < 4; ++kk) {
          const int koff = (kk * 64 + lg * 16) ^ aswz;
          const bf16x8 a0 = *(const bf16x8*)(encL + abase0 + koff);
          const bf16x8 a1 = *(const bf16x8*)(encL + abase0 + 4096 + koff);
          const bf16x8 b0 = *(const bf16x8*)(Bl + cbuf + bbase +
                                             ((kk * 64 + lg * 16) ^ bswz));
          acc[c8][0] = __builtin_amdgcn_mfma_f32_16x16x32_bf16(a0, b0, acc[c8][0], 0, 0, 0);
          acc[c8][1] = __builtin_amdgcn_mfma_f32_16x16x32_bf16(a1, b0, acc[c8][1], 0, 0, 0);
        }
        __builtin_amdgcn_s_setprio(0);
        bsel = (bsel + 1 == 3) ? 0 : bsel + 1;
        nb = (nb + 1 == 3) ? 0 : nb + 1;
      }
    }

    // half-epilogue: tanh + v-weighted column reduction (registers only)
#pragma unroll
    for (int c8 = 0; c8 < 8; ++c8) {
      const int colA = hh * 512 + c8 * 64 + wc * 16 + lm;
      const float uu = ub[colA], vv = vvec[colA];
#pragma unroll
      for (int j = 0; j < 4; ++j) {
        rowp0[j] += ftanh(acc[c8][0][j] + uu) * vv;
        rowp1[j] += ftanh(acc[c8][1][j] + uu) * vv;
      }
    }
  }

  // reduce over the 16 col-lanes (lm) of each fragment group
#pragma unroll
  for (int m = 1; m < 16; m <<= 1) {
#pragma unroll
    for (int j = 0; j < 4; ++j) {
      rowp0[j] += __shfl_xor(rowp0[j], m, 64);
      rowp1[j] += __shfl_xor(rowp1[j], m, 64);
    }
  }
  if (lm == 0) {
#pragma unroll
    for (int j = 0; j < 4; ++j) {
      sred[wc * 64 + wr * 32 + lg * 4 + j] = rowp0[j];
      sred[wc * 64 + wr * 32 + 16 + lg * 4 + j] = rowp1[j];
    }
  }
  __syncthreads();
  if (t < 64) {
    out[32768 + m0 + t] =
        sred[t] + sred[64 + t] + sred[128 + t] + sred[192 + t];
  }
}

// ---------------- masked softmax over L, in place on out[32768..] --------
__global__ __launch_bounds__(256) void softmax_kernel(
    float* __restrict__ out, const int* __restrict__ mask) {
  __shared__ float wred[4];
  const int bidx = blockIdx.x;
  const int t = threadIdx.x;
  float* sc = out + 32768 + (size_t)bidx * 2048;
  const int* mk = mask + (size_t)bidx * 2048;
  const float4 s0 = *(const float4*)(sc + t * 8);
  const float4 s1 = *(const float4*)(sc + t * 8 + 4);
  const int4 q0 = *(const int4*)(mk + t * 8);
  const int4 q1 = *(const int4*)(mk + t * 8 + 4);
  float v[8] = {s0.x, s0.y, s0.z, s0.w, s1.x, s1.y, s1.z, s1.w};
  int q[8] = {q0.x, q0.y, q0.z, q0.w, q1.x, q1.y, q1.z, q1.w};
  float mx = -3.0e38f;
#pragma unroll
  for (int j = 0; j < 8; ++j) if (q[j] != 0) mx = fmaxf(mx, v[j]);
#pragma unroll
  for (int m = 1; m < 64; m <<= 1) mx = fmaxf(mx, __shfl_xor(mx, m, 64));
  if ((t & 63) == 0) wred[t >> 6] = mx;
  __syncthreads();
  mx = fmaxf(fmaxf(wred[0], wred[1]), fmaxf(wred[2], wred[3]));
  __syncthreads();
  float pp[8]; float sum = 0.f;
#pragma unroll
  for (int j = 0; j < 8; ++j) {
    pp[j] = (q[j] != 0) ? __expf(v[j] - mx) : 0.f;
    sum += pp[j];
  }
#pragma unroll
  for (int m = 1; m < 64; m <<= 1) sum += __shfl_xor(sum, m, 64);
  if ((t & 63) == 0) wred[t >> 6] = sum;
  __syncthreads();
  sum = (wred[0] + wred[1]) + (wred[2] + wred[3]);
  const float inv = 1.0f / sum;
  const float4 o0 = {pp[0] * inv, pp[1] * inv, pp[2] * inv, pp[3] * inv};
  const float4 o1 = {pp[4] * inv, pp[5] * inv, pp[6] * inv, pp[7] * inv};
  *(float4*)(sc + t * 8) = o0;
  *(float4*)(sc + t * 8 + 4) = o1;
}

// ---------------- context[b][e] = sum_l attn[b][l] * enc[b][l][e] --------
__global__ __launch_bounds__(256) void context_kernel(
    const float* __restrict__ enc, float* __restrict__ out) {
  __shared__ __align__(16) float attnS[2048];
  __shared__ __align__(16) float red[8 * 128];
  const int bid = blockIdx.x;
  const int b = bid >> 3, ec = bid & 7;
  const int e0 = ec * 128;
  const int t = threadIdx.x;
  const float* attn = out + 32768 + (size_t)b * 2048;
#pragma unroll
  for (int i = 0; i < 8; ++i) attnS[i * 256 + t] = attn[i * 256 + t];
  __syncthreads();
  const int el = (t & 31) * 4;
  const int ls = t >> 5;
  f32x4 acc = {0.f, 0.f, 0.f, 0.f};
  const float* ebase = enc + (size_t)b * 2048 * 1024 + e0 + el;
  for (int l2 = ls; l2 < 2048; l2 += 8) {
    const float a = attnS[l2];
    const float4 ev = *(const float4*)(ebase + (size_t)l2 * 1024);
    acc[0] = fmaf(a, ev.x, acc[0]);
    acc[1] = fmaf(a, ev.y, acc[1]);
    acc[2] = fmaf(a, ev.z, acc[2]);
    acc[3] = fmaf(a, ev.w, acc[3]);
  }
  *(f32x4*)(red + ls * 128 + el) = acc;
  __syncthreads();
  if (t < 128) {
    float s = 0.f;
#pragma unroll
    for (int i = 0; i < 8; ++i) s += red[i * 128 + t];
    out[(size_t)b * 1024 + e0 + t] = s;
  }
}

extern "C" void kernel_launch(void* const* d_in, const int* in_sizes, int n_in,
                              void* d_out, int out_size, void* d_ws,
                              size_t ws_size, hipStream_t stream) {
  const float* enc = (const float*)d_in[0];
  const float* dec = (const float*)d_in[1];
  const int* mask = (const int*)d_in[2];
  const float* W1 = (const float*)d_in[3];
  const float* W2 = (const float*)d_in[4];
  const float* v = (const float*)d_in[5];
  float* out = (float*)d_out;
  char* ws = (char*)d_ws;
  unsigned short* w1b = (unsigned short*)ws; /* 2 MB pre-swizzled bf16 W1 */
  float* u = (float*)(ws + (2u << 20));      /* 128 KB dec projection */

  w1cvt_kernel<<<512, 256, 0, stream>>>(W1, w1b);
  dec_proj_kernel<<<1024, 256, 0, stream>>>(dec, W2, u);
  scores_kernel<<<1024, 512, 0, stream>>>(enc, w1b, u, v, out);
  softmax_kernel<<<32, 256, 0, stream>>>(out, mask);
  context_kernel<<<256, 256, 0, stream>>>(enc, out);
}